// Round 1
// baseline (293.780 us; speedup 1.0000x reference)
//
#include <hip/hip_runtime.h>

// MemoryEfficientAttention: x->(Q,K,V) proj (split-bf16x3 MFMA), chunked-mask
// flash attention (bf16 MFMA), O-proj (split-bf16x3). fp32 in/out.
// Mask semantics: past blocks masked, diagonal block causal, future blocks visible.

#define BT 4096      // B*T
#define TSEQ 2048
#define CDIM 1024

typedef __attribute__((ext_vector_type(8))) short bf16x8;
typedef __attribute__((ext_vector_type(4))) float f32x4;
typedef __attribute__((ext_vector_type(4))) float float4v;
typedef __attribute__((ext_vector_type(4))) unsigned short u16x4;

__device__ __forceinline__ unsigned short f2bf(float x){
  union { float f; unsigned int u; } c; c.f = x;
  unsigned int r = c.u + 0x7FFFu + ((c.u >> 16) & 1u);
  return (unsigned short)(r >> 16);
}
__device__ __forceinline__ float bf2f(unsigned short h){
  union { unsigned int u; float f; } c; c.u = ((unsigned int)h) << 16;
  return c.f;
}
__device__ __forceinline__ f32x4 zero4(){ f32x4 v; v[0]=0.f; v[1]=0.f; v[2]=0.f; v[3]=0.f; return v; }

// async global->LDS, 16B per lane; LDS dest = wave-uniform base + lane*16
#define GLDS16(g, l) __builtin_amdgcn_global_load_lds( \
  (const __attribute__((address_space(1))) void*)(g), \
  (__attribute__((address_space(3))) void*)(l), 16, 0, 0)

// ---------------- split fp32 -> bf16 hi/lo ----------------
__global__ __launch_bounds__(256) void k_split(const float* __restrict__ src,
    unsigned short* __restrict__ dh, unsigned short* __restrict__ dl, int n4){
  int i = blockIdx.x * 256 + threadIdx.x;
  int stride = gridDim.x * 256;
  for (; i < n4; i += stride){
    float4v v = ((const float4v*)src)[i];
    u16x4 h, l;
    #pragma unroll
    for (int j = 0; j < 4; ++j){
      unsigned short hi = f2bf(v[j]);
      h[j] = hi;
      l[j] = f2bf(v[j] - bf2f(hi));
    }
    ((u16x4*)dh)[i] = h;
    ((u16x4*)dl)[i] = l;
  }
}

__global__ __launch_bounds__(256) void k_split_w(
    const float* __restrict__ Wq, const float* __restrict__ Wk,
    const float* __restrict__ Wv, const float* __restrict__ Wo,
    const float* __restrict__ bq, const float* __restrict__ bk, const float* __restrict__ bv,
    unsigned short* __restrict__ wh, unsigned short* __restrict__ wl,
    float* __restrict__ bias_cat){
  int i = blockIdx.x * 256 + threadIdx.x;      // float4 index, 4096 blocks -> exactly 1M
  const float* srcs[4] = {Wq, Wk, Wv, Wo};
  int sel = i >> 18;                            // 262144 float4 per matrix
  float4v v = ((const float4v*)srcs[sel])[i & 0x3FFFF];
  u16x4 h, l;
  #pragma unroll
  for (int j = 0; j < 4; ++j){
    unsigned short hi = f2bf(v[j]);
    h[j] = hi;
    l[j] = f2bf(v[j] - bf2f(hi));
  }
  ((u16x4*)wh)[i] = h;
  ((u16x4*)wl)[i] = l;
  if (i < 3072){
    const float* bs[3] = {bq, bk, bv};
    bias_cat[i] = bs[i >> 10][i & 1023];
  }
}

// ---------------- split-precision GEMM: out = A @ W^T + bias ----------------
// A: [M=4096][K=1024] bf16 hi/lo, B(W): [N][1024] bf16 hi/lo, both K-contiguous.
// MODE 0: N=3072 fused QKV -> scatter Q[b,h,t,d], K[b,h,t,d], Vt[b,h,d,t] (bf16)
// MODE 1: N=1024 -> fp32 out + bias
template<int BN, int MODE>
__global__ __launch_bounds__(256) void k_gemm(
    const unsigned short* __restrict__ Ah, const unsigned short* __restrict__ Al,
    const unsigned short* __restrict__ Bh, const unsigned short* __restrict__ Bl,
    const float* __restrict__ bias,
    unsigned short* __restrict__ oq, unsigned short* __restrict__ okk,
    unsigned short* __restrict__ ov, float* __restrict__ fo)
{
  constexpr int MF = (BN == 128) ? 4 : 2;
  constexpr int NF = 4;
  constexpr int BISS = (BN == 128) ? 2 : 1;
  __shared__ unsigned short As[2][128*32];     // [hi/lo][row 64B, chunk-swizzled]
  __shared__ unsigned short Bs[2][BN*32];

  const int tid  = threadIdx.x;
  const int wid  = tid >> 6;
  const int lane = tid & 63;
  const int l15  = lane & 15;
  const int kg   = lane >> 4;
  const int m0 = blockIdx.y * 128;
  const int n0 = blockIdx.x * BN;
  const int wrb = (BN == 128) ? (wid >> 1) * 64 : wid * 32;
  const int wcb = (BN == 128) ? (wid & 1) * 64 : 0;

  f32x4 acc[MF][NF];
  #pragma unroll
  for (int a = 0; a < MF; ++a)
    #pragma unroll
    for (int b = 0; b < NF; ++b) acc[a][b] = zero4();

  for (int k0 = 0; k0 < 1024; k0 += 32){
    // stage: LDS linear dest, inverse-swizzled global source (chunk ^= (row>>1)&3)
    #pragma unroll
    for (int p = 0; p < 2; ++p){
      const unsigned short* Asrc = p ? Al : Ah;
      #pragma unroll
      for (int iss = 0; iss < 2; ++iss){
        int L = iss*2048 + tid*8;
        int row = L >> 5;
        int ck = ((L >> 3) & 3) ^ ((row >> 1) & 3);
        GLDS16(Asrc + (size_t)(m0 + row)*1024 + k0 + ck*8,
               (char*)(&As[p][0]) + iss*4096 + wid*1024);
      }
      const unsigned short* Bsrc = p ? Bl : Bh;
      #pragma unroll
      for (int iss = 0; iss < BISS; ++iss){
        int L = iss*2048 + tid*8;
        int row = L >> 5;
        int ck = ((L >> 3) & 3) ^ ((row >> 1) & 3);
        GLDS16(Bsrc + (size_t)(n0 + row)*1024 + k0 + ck*8,
               (char*)(&Bs[p][0]) + iss*4096 + wid*1024);
      }
    }
    __syncthreads();

    bf16x8 af[MF][2];
    #pragma unroll
    for (int mf = 0; mf < MF; ++mf){
      int r = wrb + mf*16 + l15;
      int ckpos = kg ^ ((r >> 1) & 3);
      af[mf][0] = *(const bf16x8*)((const char*)(&As[0][0]) + r*64 + ckpos*16);
      af[mf][1] = *(const bf16x8*)((const char*)(&As[1][0]) + r*64 + ckpos*16);
    }
    #pragma unroll
    for (int nf = 0; nf < NF; ++nf){
      int r = wcb + nf*16 + l15;
      int ckpos = kg ^ ((r >> 1) & 3);
      bf16x8 bhv = *(const bf16x8*)((const char*)(&Bs[0][0]) + r*64 + ckpos*16);
      bf16x8 blv = *(const bf16x8*)((const char*)(&Bs[1][0]) + r*64 + ckpos*16);
      #pragma unroll
      for (int mf = 0; mf < MF; ++mf){
        acc[mf][nf] = __builtin_amdgcn_mfma_f32_16x16x32_bf16(af[mf][0], bhv, acc[mf][nf], 0,0,0);
        acc[mf][nf] = __builtin_amdgcn_mfma_f32_16x16x32_bf16(af[mf][0], blv, acc[mf][nf], 0,0,0);
        acc[mf][nf] = __builtin_amdgcn_mfma_f32_16x16x32_bf16(af[mf][1], bhv, acc[mf][nf], 0,0,0);
      }
    }
    __syncthreads();
  }

  // epilogue: C/D layout col=lane&15, row=(lane>>4)*4+j (m89/m91 verified)
  #pragma unroll
  for (int mf = 0; mf < MF; ++mf){
    #pragma unroll
    for (int nf = 0; nf < NF; ++nf){
      int colg = n0 + wcb + nf*16 + l15;
      float bb = bias[colg];
      #pragma unroll
      for (int j = 0; j < 4; ++j){
        int r = m0 + wrb + mf*16 + kg*4 + j;
        float val = acc[mf][nf][j] + bb;
        if (MODE == 1){
          fo[(size_t)r*1024 + colg] = val;
        } else {
          int bi = r >> 11, tt = r & 2047;
          int mat = colg >> 10, jj = colg & 1023;
          int h = jj >> 6, d = jj & 63;
          size_t bh_ = (size_t)(bi*16 + h);
          unsigned short vv = f2bf(val);
          if (mat == 0)      oq [(bh_*2048 + tt)*64 + d] = vv;
          else if (mat == 1) okk[(bh_*2048 + tt)*64 + d] = vv;
          else               ov [(bh_*64 + d)*2048 + tt] = vv;   // V pre-transposed
        }
      }
    }
  }
}

// ---------------- flash attention with chunk mask ----------------
// grid: 1024 blocks = qi*32 + bh (heavy qi first). 4 waves x 16 q-rows.
// Scans key-blocks kb = qi..31; diagonal block causal, rest unmasked.
__global__ __launch_bounds__(256) void k_attn(
    const unsigned short* __restrict__ Qg, const unsigned short* __restrict__ Kg,
    const unsigned short* __restrict__ Vtg, const float* __restrict__ scale_p,
    unsigned short* __restrict__ Ohi, unsigned short* __restrict__ Olo)
{
  __shared__ unsigned short Qs[64*64];
  __shared__ unsigned short Ks[64*64];
  __shared__ unsigned short Vts[64*64];   // rows = d, cols = kv
  __shared__ unsigned short Ps[4][16*64]; // per-wave P tile

  const int tid  = threadIdx.x;
  const int wid  = tid >> 6;
  const int lane = tid & 63;
  const int l15  = lane & 15;
  const int kg   = lane >> 4;
  const int qi = blockIdx.x >> 5;
  const int bh = blockIdx.x & 31;
  const size_t base = (size_t)bh * (2048*64);
  const float scale = scale_p[0];

  // stage Q tile (row-swizzle chunk ^= row&7 applied on global source)
  #pragma unroll
  for (int iss = 0; iss < 2; ++iss){
    int L = iss*2048 + tid*8;
    int r = L >> 6;
    int ck = ((L >> 3) & 7) ^ (r & 7);
    GLDS16(Qg + base + (size_t)(qi*64 + r)*64 + ck*8, (char*)Qs + iss*4096 + wid*1024);
  }

  f32x4 Ofr[4];
  #pragma unroll
  for (int d = 0; d < 4; ++d) Ofr[d] = zero4();
  float mrow[4] = {-1e30f,-1e30f,-1e30f,-1e30f};
  float lrow[4] = {0.f,0.f,0.f,0.f};

  { // first K/V tile
    int kb = qi;
    #pragma unroll
    for (int iss = 0; iss < 2; ++iss){
      int L = iss*2048 + tid*8;
      int r = L >> 6;
      int ck = ((L >> 3) & 7) ^ (r & 7);
      GLDS16(Kg  + base + (size_t)(kb*64 + r)*64 + ck*8, (char*)Ks  + iss*4096 + wid*1024);
      GLDS16(Vtg + base + (size_t)r*2048 + kb*64 + ck*8, (char*)Vts + iss*4096 + wid*1024);
    }
  }
  __syncthreads();

  for (int kb = qi; kb < 32; ++kb){
    // S = Q K^T (rows: this wave's 16 queries, cols: 64 keys)
    f32x4 S[4];
    #pragma unroll
    for (int nf = 0; nf < 4; ++nf) S[nf] = zero4();
    #pragma unroll
    for (int ks = 0; ks < 2; ++ks){
      int rq = wid*16 + l15;
      bf16x8 aq = *(const bf16x8*)((const char*)Qs + rq*128 + (((ks*4 + kg) ^ (rq & 7)) * 16));
      #pragma unroll
      for (int nf = 0; nf < 4; ++nf){
        int rk = nf*16 + l15;
        bf16x8 bk_ = *(const bf16x8*)((const char*)Ks + rk*128 + (((ks*4 + kg) ^ (rk & 7)) * 16));
        S[nf] = __builtin_amdgcn_mfma_f32_16x16x32_bf16(aq, bk_, S[nf], 0,0,0);
      }
    }
    // scale + mask (diagonal block: causal within block)
    #pragma unroll
    for (int nf = 0; nf < 4; ++nf){
      #pragma unroll
      for (int j = 0; j < 4; ++j){
        float s = S[nf][j] * scale;
        if (kb == qi){
          int ql = wid*16 + kg*4 + j;
          int kk = nf*16 + l15;
          if (kk > ql) s = -1e30f;
        }
        S[nf][j] = s;
      }
    }
    // online softmax (rows live on lanes sharing kg; reduce over low 4 lane bits)
    float rm[4], fj[4], rs[4];
    #pragma unroll
    for (int j = 0; j < 4; ++j)
      rm[j] = fmaxf(fmaxf(S[0][j], S[1][j]), fmaxf(S[2][j], S[3][j]));
    #pragma unroll
    for (int d = 1; d < 16; d <<= 1){
      #pragma unroll
      for (int j = 0; j < 4; ++j) rm[j] = fmaxf(rm[j], __shfl_xor(rm[j], d, 64));
    }
    #pragma unroll
    for (int j = 0; j < 4; ++j){
      float mn = fmaxf(mrow[j], rm[j]);
      fj[j] = __expf(mrow[j] - mn);
      mrow[j] = mn;
      rs[j] = 0.f;
    }
    #pragma unroll
    for (int nf = 0; nf < 4; ++nf){
      #pragma unroll
      for (int j = 0; j < 4; ++j){
        float p = __expf(S[nf][j] - mrow[j]);
        S[nf][j] = p;
        rs[j] += p;
      }
    }
    #pragma unroll
    for (int d = 1; d < 16; d <<= 1){
      #pragma unroll
      for (int j = 0; j < 4; ++j) rs[j] += __shfl_xor(rs[j], d, 64);
    }
    #pragma unroll
    for (int j = 0; j < 4; ++j) lrow[j] = lrow[j]*fj[j] + rs[j];
    #pragma unroll
    for (int df = 0; df < 4; ++df){
      #pragma unroll
      for (int j = 0; j < 4; ++j) Ofr[df][j] *= fj[j];
    }
    // P -> LDS (bf16, swizzled), then PV
    #pragma unroll
    for (int nf = 0; nf < 4; ++nf){
      #pragma unroll
      for (int j = 0; j < 4; ++j){
        int r = kg*4 + j;
        int c2 = (nf*16 + l15) * 2;
        *(unsigned short*)((char*)(&Ps[wid][0]) + r*128 + (c2 ^ ((r & 7) << 4))) = f2bf(S[nf][j]);
      }
    }
    #pragma unroll
    for (int ks = 0; ks < 2; ++ks){
      bf16x8 pa = *(const bf16x8*)((const char*)(&Ps[wid][0]) + l15*128 + (((ks*4 + kg) ^ (l15 & 7)) * 16));
      #pragma unroll
      for (int df = 0; df < 4; ++df){
        int rv = df*16 + l15;
        bf16x8 vb = *(const bf16x8*)((const char*)Vts + rv*128 + (((ks*4 + kg) ^ (rv & 7)) * 16));
        Ofr[df] = __builtin_amdgcn_mfma_f32_16x16x32_bf16(pa, vb, Ofr[df], 0,0,0);
      }
    }
    __syncthreads();
    if (kb < 31){
      int kb2 = kb + 1;
      #pragma unroll
      for (int iss = 0; iss < 2; ++iss){
        int L = iss*2048 + tid*8;
        int r = L >> 6;
        int ck = ((L >> 3) & 7) ^ (r & 7);
        GLDS16(Kg  + base + (size_t)(kb2*64 + r)*64 + ck*8, (char*)Ks  + iss*4096 + wid*1024);
        GLDS16(Vtg + base + (size_t)r*2048 + kb2*64 + ck*8, (char*)Vts + iss*4096 + wid*1024);
      }
      __syncthreads();
    }
  }

  // epilogue: O /= l, store hi/lo split for the final projection
  const int bi = bh >> 4, h = bh & 15;
  #pragma unroll
  for (int df = 0; df < 4; ++df){
    #pragma unroll
    for (int j = 0; j < 4; ++j){
      int tt = qi*64 + wid*16 + kg*4 + j;
      size_t row = (size_t)(bi*2048 + tt);
      int col = h*64 + df*16 + l15;
      float v = Ofr[df][j] / lrow[j];
      unsigned short hv = f2bf(v);
      Ohi[row*1024 + col] = hv;
      Olo[row*1024 + col] = f2bf(v - bf2f(hv));
    }
  }
}

extern "C" void kernel_launch(void* const* d_in, const int* in_sizes, int n_in,
                              void* d_out, int out_size, void* d_ws, size_t ws_size,
                              hipStream_t stream){
  const float* x  = (const float*)d_in[0];
  const float* Wq = (const float*)d_in[1];
  const float* bq = (const float*)d_in[2];
  const float* Wk = (const float*)d_in[3];
  const float* bk = (const float*)d_in[4];
  const float* Wv = (const float*)d_in[5];
  const float* bv = (const float*)d_in[6];
  const float* Wo = (const float*)d_in[7];
  const float* bo = (const float*)d_in[8];
  const float* scale = (const float*)d_in[9];
  float* out = (float*)d_out;

  char* ws = (char*)d_ws;
  const size_t MB = 1024*1024;
  unsigned short* xh  = (unsigned short*)(ws + 0*MB);
  unsigned short* xl  = (unsigned short*)(ws + 8*MB);
  unsigned short* wh  = (unsigned short*)(ws + 16*MB);
  unsigned short* wl  = (unsigned short*)(ws + 24*MB);
  unsigned short* Qb  = (unsigned short*)(ws + 32*MB);
  unsigned short* Kb  = (unsigned short*)(ws + 40*MB);
  unsigned short* Vtb = (unsigned short*)(ws + 48*MB);
  unsigned short* Ohi = (unsigned short*)(ws + 56*MB);
  unsigned short* Olo = (unsigned short*)(ws + 64*MB);
  float* bias_cat     = (float*)(ws + 72*MB);

  hipLaunchKernelGGL(k_split, dim3(2048), dim3(256), 0, stream, x, xh, xl, 1048576);
  hipLaunchKernelGGL(k_split_w, dim3(4096), dim3(256), 0, stream,
                     Wq, Wk, Wv, Wo, bq, bk, bv, wh, wl, bias_cat);
  hipLaunchKernelGGL((k_gemm<128,0>), dim3(24,32), dim3(256), 0, stream,
                     xh, xl, wh, wl, bias_cat, Qb, Kb, Vtb, (float*)nullptr);
  hipLaunchKernelGGL(k_attn, dim3(1024), dim3(256), 0, stream, Qb, Kb, Vtb, scale, Ohi, Olo);
  hipLaunchKernelGGL((k_gemm<64,1>), dim3(16,32), dim3(256), 0, stream,
                     Ohi, Olo, wh + 3u*1048576u, wl + 3u*1048576u, bo,
                     (unsigned short*)nullptr, (unsigned short*)nullptr,
                     (unsigned short*)nullptr, out);
}

// Round 3
// 229.535 us; speedup vs baseline: 1.2799x; 1.2799x over previous
//
#include <hip/hip_runtime.h>

// MemoryEfficientAttention: x->(Q,K,V) proj (plain bf16 MFMA), chunked-mask
// flash attention (bf16 MFMA), O-proj (split-A bf16x2 MFMA). fp32 in/out.
// Mask semantics: past blocks masked, diagonal block causal, future blocks visible.

#define BT 4096      // B*T
#define TSEQ 2048
#define CDIM 1024

typedef __attribute__((ext_vector_type(8))) short bf16x8;
typedef __attribute__((ext_vector_type(4))) float f32x4;
typedef __attribute__((ext_vector_type(4))) float float4v;
typedef __attribute__((ext_vector_type(4))) unsigned short u16x4;

__device__ __forceinline__ unsigned short f2bf(float x){
  union { float f; unsigned int u; } c; c.f = x;
  unsigned int r = c.u + 0x7FFFu + ((c.u >> 16) & 1u);
  return (unsigned short)(r >> 16);
}
__device__ __forceinline__ float bf2f(unsigned short h){
  union { unsigned int u; float f; } c; c.u = ((unsigned int)h) << 16;
  return c.f;
}
__device__ __forceinline__ f32x4 zero4(){ f32x4 v; v[0]=0.f; v[1]=0.f; v[2]=0.f; v[3]=0.f; return v; }

// async global->LDS, 16B per lane; LDS dest = wave-uniform base + lane*16
#define GLDS16(g, l) __builtin_amdgcn_global_load_lds( \
  (const __attribute__((address_space(1))) void*)(g), \
  (__attribute__((address_space(3))) void*)(l), 16, 0, 0)

// ---------------- prep: cast x and all weights to bf16, gather biases ----------------
__global__ __launch_bounds__(256) void k_prep(
    const float* __restrict__ x,
    const float* __restrict__ Wq, const float* __restrict__ Wk,
    const float* __restrict__ Wv, const float* __restrict__ Wo,
    const float* __restrict__ bq, const float* __restrict__ bk, const float* __restrict__ bv,
    unsigned short* __restrict__ xh, unsigned short* __restrict__ wh,
    float* __restrict__ bias_cat){
  const int NX = 1048576;                     // x float4 count (4096*1024/4)
  const int NTOT = 2097152;                   // + 4 weight matrices (4*1024*1024/4)
  int i = blockIdx.x * 256 + threadIdx.x;
  if (i < 3072){
    const float* bs[3] = {bq, bk, bv};
    bias_cat[i] = bs[i >> 10][i & 1023];
  }
  int stride = gridDim.x * 256;
  for (; i < NTOT; i += stride){
    float4v v;
    u16x4 h;
    if (i < NX){
      v = ((const float4v*)x)[i];
      #pragma unroll
      for (int j = 0; j < 4; ++j) h[j] = f2bf(v[j]);
      ((u16x4*)xh)[i] = h;
    } else {
      int jj = i - NX;
      const float* srcs[4] = {Wq, Wk, Wv, Wo};
      v = ((const float4v*)srcs[jj >> 18])[jj & 0x3FFFF];
      #pragma unroll
      for (int j = 0; j < 4; ++j) h[j] = f2bf(v[j]);
      ((u16x4*)wh)[jj] = h;
    }
  }
}

// ---------------- GEMM: out = A @ W^T + bias ----------------
// A: [M=4096][K=1024] bf16 (hi, + lo if SPLITA), B(W): [N][1024] bf16, K-contiguous.
// MODE 0: N=3072 fused QKV -> scatter Q[b,h,t,d], K[b,h,t,d], Vt[b,h,d,t] (bf16)
// MODE 1: N=1024 -> fp32 out + bias
template<int BN, int MODE, int SPLITA>
__global__ __launch_bounds__(256) void k_gemm(
    const unsigned short* __restrict__ Ah, const unsigned short* __restrict__ Al,
    const unsigned short* __restrict__ Bh,
    const float* __restrict__ bias,
    unsigned short* __restrict__ oq, unsigned short* __restrict__ okk,
    unsigned short* __restrict__ ov, float* __restrict__ fo)
{
  constexpr int MF = (BN == 128) ? 4 : 2;
  constexpr int NF = 4;
  constexpr int BISS = (BN == 128) ? 2 : 1;
  constexpr int NA = SPLITA ? 2 : 1;
  __shared__ unsigned short As[NA][128*32];    // [pass][row 64B, chunk-swizzled]
  __shared__ unsigned short Bs[BN*32];

  const int tid  = threadIdx.x;
  const int wid  = tid >> 6;
  const int lane = tid & 63;
  const int l15  = lane & 15;
  const int kg   = lane >> 4;
  const int m0 = blockIdx.y * 128;
  const int n0 = blockIdx.x * BN;
  const int wrb = (BN == 128) ? (wid >> 1) * 64 : wid * 32;
  const int wcb = (BN == 128) ? (wid & 1) * 64 : 0;

  f32x4 acc[MF][NF];
  #pragma unroll
  for (int a = 0; a < MF; ++a)
    #pragma unroll
    for (int b = 0; b < NF; ++b) acc[a][b] = zero4();

  for (int k0 = 0; k0 < 1024; k0 += 32){
    // stage: LDS linear dest, inverse-swizzled global source (chunk ^= (row>>1)&3)
    #pragma unroll
    for (int p = 0; p < NA; ++p){
      const unsigned short* Asrc = p ? Al : Ah;
      #pragma unroll
      for (int iss = 0; iss < 2; ++iss){
        int L = iss*2048 + tid*8;
        int row = L >> 5;
        int ck = ((L >> 3) & 3) ^ ((row >> 1) & 3);
        GLDS16(Asrc + (size_t)(m0 + row)*1024 + k0 + ck*8,
               (char*)(&As[p][0]) + iss*4096 + wid*1024);
      }
    }
    #pragma unroll
    for (int iss = 0; iss < BISS; ++iss){
      int L = iss*2048 + tid*8;
      int row = L >> 5;
      int ck = ((L >> 3) & 3) ^ ((row >> 1) & 3);
      GLDS16(Bh + (size_t)(n0 + row)*1024 + k0 + ck*8,
             (char*)(&Bs[0]) + iss*4096 + wid*1024);
    }
    __syncthreads();

    bf16x8 af[MF][NA];
    #pragma unroll
    for (int mf = 0; mf < MF; ++mf){
      int r = wrb + mf*16 + l15;
      int ckpos = kg ^ ((r >> 1) & 3);
      #pragma unroll
      for (int p = 0; p < NA; ++p)
        af[mf][p] = *(const bf16x8*)((const char*)(&As[p][0]) + r*64 + ckpos*16);
    }
    #pragma unroll
    for (int nf = 0; nf < NF; ++nf){
      int r = wcb + nf*16 + l15;
      int ckpos = kg ^ ((r >> 1) & 3);
      bf16x8 bhv = *(const bf16x8*)((const char*)(&Bs[0]) + r*64 + ckpos*16);
      #pragma unroll
      for (int mf = 0; mf < MF; ++mf){
        acc[mf][nf] = __builtin_amdgcn_mfma_f32_16x16x32_bf16(af[mf][0], bhv, acc[mf][nf], 0,0,0);
        if (SPLITA)
          acc[mf][nf] = __builtin_amdgcn_mfma_f32_16x16x32_bf16(af[mf][1], bhv, acc[mf][nf], 0,0,0);
      }
    }
    __syncthreads();
  }

  // epilogue: C/D layout col=lane&15, row=(lane>>4)*4+j (m89/m91 verified)
  #pragma unroll
  for (int mf = 0; mf < MF; ++mf){
    #pragma unroll
    for (int nf = 0; nf < NF; ++nf){
      int colg = n0 + wcb + nf*16 + l15;
      float bb = bias[colg];
      #pragma unroll
      for (int j = 0; j < 4; ++j){
        int r = m0 + wrb + mf*16 + kg*4 + j;
        float val = acc[mf][nf][j] + bb;
        if (MODE == 1){
          fo[(size_t)r*1024 + colg] = val;
        } else {
          int bi = r >> 11, tt = r & 2047;
          int mat = colg >> 10, jj = colg & 1023;
          int h = jj >> 6, d = jj & 63;
          size_t bh_ = (size_t)(bi*16 + h);
          unsigned short vv = f2bf(val);
          if (mat == 0)      oq [(bh_*2048 + tt)*64 + d] = vv;
          else if (mat == 1) okk[(bh_*2048 + tt)*64 + d] = vv;
          else               ov [(bh_*64 + d)*2048 + tt] = vv;   // V pre-transposed
        }
      }
    }
  }
}

// ---------------- flash attention with chunk mask ----------------
// grid: 1024 blocks = qi*32 + bh (heavy qi first). 4 waves x 16 q-rows.
// Scans key-blocks kb = qi..31; diagonal block causal, rest unmasked.
__global__ __launch_bounds__(256) void k_attn(
    const unsigned short* __restrict__ Qg, const unsigned short* __restrict__ Kg,
    const unsigned short* __restrict__ Vtg, const float* __restrict__ scale_p,
    unsigned short* __restrict__ Ohi, unsigned short* __restrict__ Olo)
{
  __shared__ unsigned short Qs[64*64];
  __shared__ unsigned short Ks[64*64];
  __shared__ unsigned short Vts[64*64];   // rows = d, cols = kv
  __shared__ unsigned short Ps[4][16*64]; // per-wave P tile

  const int tid  = threadIdx.x;
  const int wid  = tid >> 6;
  const int lane = tid & 63;
  const int l15  = lane & 15;
  const int kg   = lane >> 4;
  const int qi = blockIdx.x >> 5;
  const int bh = blockIdx.x & 31;
  const size_t base = (size_t)bh * (2048*64);
  const float scale = scale_p[0];

  // stage Q tile (row-swizzle chunk ^= row&7 applied on global source)
  #pragma unroll
  for (int iss = 0; iss < 2; ++iss){
    int L = iss*2048 + tid*8;
    int r = L >> 6;
    int ck = ((L >> 3) & 7) ^ (r & 7);
    GLDS16(Qg + base + (size_t)(qi*64 + r)*64 + ck*8, (char*)Qs + iss*4096 + wid*1024);
  }

  f32x4 Ofr[4];
  #pragma unroll
  for (int d = 0; d < 4; ++d) Ofr[d] = zero4();
  float mrow[4] = {-1e30f,-1e30f,-1e30f,-1e30f};
  float lrow[4] = {0.f,0.f,0.f,0.f};

  { // first K/V tile
    int kb = qi;
    #pragma unroll
    for (int iss = 0; iss < 2; ++iss){
      int L = iss*2048 + tid*8;
      int r = L >> 6;
      int ck = ((L >> 3) & 7) ^ (r & 7);
      GLDS16(Kg  + base + (size_t)(kb*64 + r)*64 + ck*8, (char*)Ks  + iss*4096 + wid*1024);
      GLDS16(Vtg + base + (size_t)r*2048 + kb*64 + ck*8, (char*)Vts + iss*4096 + wid*1024);
    }
  }
  __syncthreads();

  for (int kb = qi; kb < 32; ++kb){
    // S = Q K^T (rows: this wave's 16 queries, cols: 64 keys)
    f32x4 S[4];
    #pragma unroll
    for (int nf = 0; nf < 4; ++nf) S[nf] = zero4();
    #pragma unroll
    for (int ks = 0; ks < 2; ++ks){
      int rq = wid*16 + l15;
      bf16x8 aq = *(const bf16x8*)((const char*)Qs + rq*128 + (((ks*4 + kg) ^ (rq & 7)) * 16));
      #pragma unroll
      for (int nf = 0; nf < 4; ++nf){
        int rk = nf*16 + l15;
        bf16x8 bk_ = *(const bf16x8*)((const char*)Ks + rk*128 + (((ks*4 + kg) ^ (rk & 7)) * 16));
        S[nf] = __builtin_amdgcn_mfma_f32_16x16x32_bf16(aq, bk_, S[nf], 0,0,0);
      }
    }
    // scale + mask (diagonal block: causal within block)
    #pragma unroll
    for (int nf = 0; nf < 4; ++nf){
      #pragma unroll
      for (int j = 0; j < 4; ++j){
        float s = S[nf][j] * scale;
        if (kb == qi){
          int ql = wid*16 + kg*4 + j;
          int kk = nf*16 + l15;
          if (kk > ql) s = -1e30f;
        }
        S[nf][j] = s;
      }
    }
    // online softmax (rows live on lanes sharing kg; reduce over low 4 lane bits)
    float rm[4], fj[4], rs[4];
    #pragma unroll
    for (int j = 0; j < 4; ++j)
      rm[j] = fmaxf(fmaxf(S[0][j], S[1][j]), fmaxf(S[2][j], S[3][j]));
    #pragma unroll
    for (int d = 1; d < 16; d <<= 1){
      #pragma unroll
      for (int j = 0; j < 4; ++j) rm[j] = fmaxf(rm[j], __shfl_xor(rm[j], d, 64));
    }
    #pragma unroll
    for (int j = 0; j < 4; ++j){
      float mn = fmaxf(mrow[j], rm[j]);
      fj[j] = __expf(mrow[j] - mn);
      mrow[j] = mn;
      rs[j] = 0.f;
    }
    #pragma unroll
    for (int nf = 0; nf < 4; ++nf){
      #pragma unroll
      for (int j = 0; j < 4; ++j){
        float p = __expf(S[nf][j] - mrow[j]);
        S[nf][j] = p;
        rs[j] += p;
      }
    }
    #pragma unroll
    for (int d = 1; d < 16; d <<= 1){
      #pragma unroll
      for (int j = 0; j < 4; ++j) rs[j] += __shfl_xor(rs[j], d, 64);
    }
    #pragma unroll
    for (int j = 0; j < 4; ++j) lrow[j] = lrow[j]*fj[j] + rs[j];
    #pragma unroll
    for (int df = 0; df < 4; ++df){
      #pragma unroll
      for (int j = 0; j < 4; ++j) Ofr[df][j] *= fj[j];
    }
    // P -> LDS (bf16, swizzled), then PV
    #pragma unroll
    for (int nf = 0; nf < 4; ++nf){
      #pragma unroll
      for (int j = 0; j < 4; ++j){
        int r = kg*4 + j;
        int c2 = (nf*16 + l15) * 2;
        *(unsigned short*)((char*)(&Ps[wid][0]) + r*128 + (c2 ^ ((r & 7) << 4))) = f2bf(S[nf][j]);
      }
    }
    #pragma unroll
    for (int ks = 0; ks < 2; ++ks){
      bf16x8 pa = *(const bf16x8*)((const char*)(&Ps[wid][0]) + l15*128 + (((ks*4 + kg) ^ (l15 & 7)) * 16));
      #pragma unroll
      for (int df = 0; df < 4; ++df){
        int rv = df*16 + l15;
        bf16x8 vb = *(const bf16x8*)((const char*)Vts + rv*128 + (((ks*4 + kg) ^ (rv & 7)) * 16));
        Ofr[df] = __builtin_amdgcn_mfma_f32_16x16x32_bf16(pa, vb, Ofr[df], 0,0,0);
      }
    }
    __syncthreads();
    if (kb < 31){
      int kb2 = kb + 1;
      #pragma unroll
      for (int iss = 0; iss < 2; ++iss){
        int L = iss*2048 + tid*8;
        int r = L >> 6;
        int ck = ((L >> 3) & 7) ^ (r & 7);
        GLDS16(Kg  + base + (size_t)(kb2*64 + r)*64 + ck*8, (char*)Ks  + iss*4096 + wid*1024);
        GLDS16(Vtg + base + (size_t)r*2048 + kb2*64 + ck*8, (char*)Vts + iss*4096 + wid*1024);
      }
      __syncthreads();
    }
  }

  // epilogue: O /= l, store hi/lo split for the final projection
  const int bi = bh >> 4, h = bh & 15;
  #pragma unroll
  for (int df = 0; df < 4; ++df){
    #pragma unroll
    for (int j = 0; j < 4; ++j){
      int tt = qi*64 + wid*16 + kg*4 + j;
      size_t row = (size_t)(bi*2048 + tt);
      int col = h*64 + df*16 + l15;
      float v = Ofr[df][j] / lrow[j];
      unsigned short hv = f2bf(v);
      Ohi[row*1024 + col] = hv;
      Olo[row*1024 + col] = f2bf(v - bf2f(hv));
    }
  }
}

extern "C" void kernel_launch(void* const* d_in, const int* in_sizes, int n_in,
                              void* d_out, int out_size, void* d_ws, size_t ws_size,
                              hipStream_t stream){
  const float* x  = (const float*)d_in[0];
  const float* Wq = (const float*)d_in[1];
  const float* bq = (const float*)d_in[2];
  const float* Wk = (const float*)d_in[3];
  const float* bk = (const float*)d_in[4];
  const float* Wv = (const float*)d_in[5];
  const float* bv = (const float*)d_in[6];
  const float* Wo = (const float*)d_in[7];
  const float* bo = (const float*)d_in[8];
  const float* scale = (const float*)d_in[9];
  float* out = (float*)d_out;

  char* ws = (char*)d_ws;
  const size_t MB = 1024*1024;
  unsigned short* xh  = (unsigned short*)(ws + 0*MB);    // 8 MB
  unsigned short* wh  = (unsigned short*)(ws + 16*MB);   // 8 MB (Wq,Wk,Wv,Wo bf16)
  unsigned short* Qb  = (unsigned short*)(ws + 32*MB);
  unsigned short* Kb  = (unsigned short*)(ws + 40*MB);
  unsigned short* Vtb = (unsigned short*)(ws + 48*MB);
  unsigned short* Ohi = (unsigned short*)(ws + 56*MB);
  unsigned short* Olo = (unsigned short*)(ws + 64*MB);
  float* bias_cat     = (float*)(ws + 72*MB);

  hipLaunchKernelGGL(k_prep, dim3(2048), dim3(256), 0, stream,
                     x, Wq, Wk, Wv, Wo, bq, bk, bv, xh, wh, bias_cat);
  hipLaunchKernelGGL((k_gemm<128,0,0>), dim3(24,32), dim3(256), 0, stream,
                     xh, (const unsigned short*)nullptr, wh, bias_cat,
                     Qb, Kb, Vtb, (float*)nullptr);
  hipLaunchKernelGGL(k_attn, dim3(1024), dim3(256), 0, stream, Qb, Kb, Vtb, scale, Ohi, Olo);
  hipLaunchKernelGGL((k_gemm<64,1,1>), dim3(16,32), dim3(256), 0, stream,
                     Ohi, Olo, wh + 3u*1048576u, bo,
                     (unsigned short*)nullptr, (unsigned short*)nullptr,
                     (unsigned short*)nullptr, out);
}

// Round 4
// 214.912 us; speedup vs baseline: 1.3670x; 1.0680x over previous
//
#include <hip/hip_runtime.h>

// MemoryEfficientAttention: x->(Q,K,V) proj (bf16 MFMA, scale folded into Q),
// chunked-mask flash attention (double-swapped MFMA, q-lane-local softmax),
// O-proj (split-A bf16x2 MFMA). fp32 in/out.
// Mask: past blocks masked, diagonal block causal, future blocks visible.

typedef __attribute__((ext_vector_type(8))) short bf16x8;
typedef __attribute__((ext_vector_type(4))) float f32x4;
typedef __attribute__((ext_vector_type(4))) float float4v;
typedef __attribute__((ext_vector_type(4))) unsigned short u16x4;

__device__ __forceinline__ unsigned short f2bf(float x){
  union { float f; unsigned int u; } c; c.f = x;
  unsigned int r = c.u + 0x7FFFu + ((c.u >> 16) & 1u);
  return (unsigned short)(r >> 16);
}
__device__ __forceinline__ float bf2f(unsigned short h){
  union { unsigned int u; float f; } c; c.u = ((unsigned int)h) << 16;
  return c.f;
}
__device__ __forceinline__ f32x4 zero4(){ f32x4 v; v[0]=0.f; v[1]=0.f; v[2]=0.f; v[3]=0.f; return v; }
__device__ __forceinline__ unsigned int cvtpk(float a, float b){
  unsigned int r;
  asm("v_cvt_pk_bf16_f32 %0, %1, %2" : "=v"(r) : "v"(a), "v"(b));
  return r;
}

// async global->LDS, 16B per lane; LDS dest = wave-uniform base + lane*16
#define GLDS16(g, l) __builtin_amdgcn_global_load_lds( \
  (const __attribute__((address_space(1))) void*)(g), \
  (__attribute__((address_space(3))) void*)(l), 16, 0, 0)

// ---------------- prep: cast x and all weights to bf16, gather biases ----------------
__global__ __launch_bounds__(256) void k_prep(
    const float* __restrict__ x,
    const float* __restrict__ Wq, const float* __restrict__ Wk,
    const float* __restrict__ Wv, const float* __restrict__ Wo,
    const float* __restrict__ bq, const float* __restrict__ bk, const float* __restrict__ bv,
    unsigned short* __restrict__ xh, unsigned short* __restrict__ wh,
    float* __restrict__ bias_cat){
  const int NX = 1048576;                     // x float4 count (4096*1024/4)
  const int NTOT = 2097152;                   // + 4 weight matrices
  int i = blockIdx.x * 256 + threadIdx.x;
  if (i < 3072){
    const float* bs[3] = {bq, bk, bv};
    bias_cat[i] = bs[i >> 10][i & 1023];
  }
  int stride = gridDim.x * 256;
  for (; i < NTOT; i += stride){
    float4v v;
    u16x4 h;
    if (i < NX){
      v = ((const float4v*)x)[i];
      #pragma unroll
      for (int j = 0; j < 4; ++j) h[j] = f2bf(v[j]);
      ((u16x4*)xh)[i] = h;
    } else {
      int jj = i - NX;
      const float* srcs[4] = {Wq, Wk, Wv, Wo};
      v = ((const float4v*)srcs[jj >> 18])[jj & 0x3FFFF];
      #pragma unroll
      for (int j = 0; j < 4; ++j) h[j] = f2bf(v[j]);
      ((u16x4*)wh)[jj] = h;
    }
  }
}

// ---------------- GEMM: out = A @ W^T + bias ----------------
// MODE 0: N=3072 fused QKV -> scatter Q[b,h,t,d]*scale, K[b,h,t,d], Vt[b,h,d,t]
// MODE 1: N=1024 -> fp32 out + bias
template<int BN, int MODE, int SPLITA>
__global__ __launch_bounds__(256) void k_gemm(
    const unsigned short* __restrict__ Ah, const unsigned short* __restrict__ Al,
    const unsigned short* __restrict__ Bh,
    const float* __restrict__ bias, const float* __restrict__ scale_p,
    unsigned short* __restrict__ oq, unsigned short* __restrict__ okk,
    unsigned short* __restrict__ ov, float* __restrict__ fo)
{
  constexpr int MF = (BN == 128) ? 4 : 2;
  constexpr int NF = 4;
  constexpr int BISS = (BN == 128) ? 2 : 1;
  constexpr int NA = SPLITA ? 2 : 1;
  __shared__ unsigned short As[NA][128*32];
  __shared__ unsigned short Bs[BN*32];

  const int tid  = threadIdx.x;
  const int wid  = tid >> 6;
  const int lane = tid & 63;
  const int l15  = lane & 15;
  const int kg   = lane >> 4;
  const int m0 = blockIdx.y * 128;
  const int n0 = blockIdx.x * BN;
  const int wrb = (BN == 128) ? (wid >> 1) * 64 : wid * 32;
  const int wcb = (BN == 128) ? (wid & 1) * 64 : 0;
  const float qs = (MODE == 0) ? scale_p[0] : 0.f;

  f32x4 acc[MF][NF];
  #pragma unroll
  for (int a = 0; a < MF; ++a)
    #pragma unroll
    for (int b = 0; b < NF; ++b) acc[a][b] = zero4();

  for (int k0 = 0; k0 < 1024; k0 += 32){
    #pragma unroll
    for (int p = 0; p < NA; ++p){
      const unsigned short* Asrc = p ? Al : Ah;
      #pragma unroll
      for (int iss = 0; iss < 2; ++iss){
        int L = iss*2048 + tid*8;
        int row = L >> 5;
        int ck = ((L >> 3) & 3) ^ ((row >> 1) & 3);
        GLDS16(Asrc + (size_t)(m0 + row)*1024 + k0 + ck*8,
               (char*)(&As[p][0]) + iss*4096 + wid*1024);
      }
    }
    #pragma unroll
    for (int iss = 0; iss < BISS; ++iss){
      int L = iss*2048 + tid*8;
      int row = L >> 5;
      int ck = ((L >> 3) & 3) ^ ((row >> 1) & 3);
      GLDS16(Bh + (size_t)(n0 + row)*1024 + k0 + ck*8,
             (char*)(&Bs[0]) + iss*4096 + wid*1024);
    }
    __syncthreads();

    bf16x8 af[MF][NA];
    #pragma unroll
    for (int mf = 0; mf < MF; ++mf){
      int r = wrb + mf*16 + l15;
      int ckpos = kg ^ ((r >> 1) & 3);
      #pragma unroll
      for (int p = 0; p < NA; ++p)
        af[mf][p] = *(const bf16x8*)((const char*)(&As[p][0]) + r*64 + ckpos*16);
    }
    #pragma unroll
    for (int nf = 0; nf < NF; ++nf){
      int r = wcb + nf*16 + l15;
      int ckpos = kg ^ ((r >> 1) & 3);
      bf16x8 bhv = *(const bf16x8*)((const char*)(&Bs[0]) + r*64 + ckpos*16);
      #pragma unroll
      for (int mf = 0; mf < MF; ++mf){
        acc[mf][nf] = __builtin_amdgcn_mfma_f32_16x16x32_bf16(af[mf][0], bhv, acc[mf][nf], 0,0,0);
        if (SPLITA)
          acc[mf][nf] = __builtin_amdgcn_mfma_f32_16x16x32_bf16(af[mf][1], bhv, acc[mf][nf], 0,0,0);
      }
    }
    __syncthreads();
  }

  #pragma unroll
  for (int mf = 0; mf < MF; ++mf){
    #pragma unroll
    for (int nf = 0; nf < NF; ++nf){
      int colg = n0 + wcb + nf*16 + l15;
      float bb = bias[colg];
      #pragma unroll
      for (int j = 0; j < 4; ++j){
        int r = m0 + wrb + mf*16 + kg*4 + j;
        float val = acc[mf][nf][j] + bb;
        if (MODE == 1){
          fo[(size_t)r*1024 + colg] = val;
        } else {
          int bi = r >> 11, tt = r & 2047;
          int mat = colg >> 10, jj = colg & 1023;
          int h = jj >> 6, d = jj & 63;
          size_t bh_ = (size_t)(bi*16 + h);
          if (mat == 0)      oq [(bh_*2048 + tt)*64 + d] = f2bf(val * qs);
          else if (mat == 1) okk[(bh_*2048 + tt)*64 + d] = f2bf(val);
          else               ov [(bh_*64 + d)*2048 + tt] = f2bf(val);  // V^T
        }
      }
    }
  }
}

// ---------------- flash attention, double-swapped MFMA ----------------
// grid: 1024 = qi*32 + bh (heavy qi first). 4 waves x 16 q-rows; q is lane-local (l15).
// ST = mfma(K,Q): col=l15=q, row=kg*4+j=k.  Ot = mfma(V^T,P^T): col=l15=q, row=kg*4+j=d.
__global__ __launch_bounds__(256) void k_attn(
    const unsigned short* __restrict__ Qg, const unsigned short* __restrict__ Kg,
    const unsigned short* __restrict__ Vtg,
    unsigned short* __restrict__ Ohi, unsigned short* __restrict__ Olo)
{
  __shared__ unsigned short Qs[64*64];
  __shared__ unsigned short Ks[2][64*64];
  __shared__ unsigned short Vts[2][64*64];   // rows = d, cols = kv
  __shared__ unsigned short Pw[4][16*64];    // per-wave P^T tile, rows=q(16), swizzled

  const int tid  = threadIdx.x;
  const int wid  = tid >> 6;
  const int lane = tid & 63;
  const int l15  = lane & 15;
  const int kg   = lane >> 4;
  const int qi = blockIdx.x >> 5;
  const int bh = blockIdx.x & 31;
  const size_t base = (size_t)bh * (2048*64);

  // stage Q + first K/V tile (buf 0); swizzle chunk ^= row&7 on global source
  #pragma unroll
  for (int iss = 0; iss < 2; ++iss){
    int L = iss*2048 + tid*8;
    int r = L >> 6;
    int ck = ((L >> 3) & 7) ^ (r & 7);
    GLDS16(Qg  + base + (size_t)(qi*64 + r)*64 + ck*8, (char*)Qs + iss*4096 + wid*1024);
    GLDS16(Kg  + base + (size_t)(qi*64 + r)*64 + ck*8, (char*)(&Ks[0][0])  + iss*4096 + wid*1024);
    GLDS16(Vtg + base + (size_t)r*2048 + qi*64 + ck*8, (char*)(&Vts[0][0]) + iss*4096 + wid*1024);
  }
  __syncthreads();

  // Q fragments (constant over kb): B-operand rows = this wave's 16 q
  bf16x8 qf[2];
  {
    int rq = wid*16 + l15;
    #pragma unroll
    for (int ks = 0; ks < 2; ++ks)
      qf[ks] = *(const bf16x8*)((const char*)Qs + rq*128 + (((ks*4 + kg) ^ (rq & 7)) * 16));
  }

  f32x4 Ot[4];
  #pragma unroll
  for (int d = 0; d < 4; ++d) Ot[d] = zero4();
  float m = -1e30f, l = 0.f;
  const int qloc = wid*16 + l15;
  char* pwb = (char*)(&Pw[wid][0]) + l15*128;
  const int swz = (l15 & 7) << 4;

  for (int kb = qi; kb < 32; ++kb){
    const int buf = (kb - qi) & 1;
    // prefetch next K/V into buf^1 (drained by this iter's closing barrier)
    if (kb + 1 < 32){
      int nb = buf ^ 1, kb2 = kb + 1;
      #pragma unroll
      for (int iss = 0; iss < 2; ++iss){
        int L = iss*2048 + tid*8;
        int r = L >> 6;
        int ck = ((L >> 3) & 7) ^ (r & 7);
        GLDS16(Kg  + base + (size_t)(kb2*64 + r)*64 + ck*8, (char*)(&Ks[nb][0])  + iss*4096 + wid*1024);
        GLDS16(Vtg + base + (size_t)r*2048 + kb2*64 + ck*8, (char*)(&Vts[nb][0]) + iss*4096 + wid*1024);
      }
    }
    // S^T = K·Q^T : ST[nf][j] = S[q=l15][k=nf*16+kg*4+j] (scale pre-folded into Q)
    f32x4 ST[4];
    #pragma unroll
    for (int nf = 0; nf < 4; ++nf) ST[nf] = zero4();
    #pragma unroll
    for (int ks = 0; ks < 2; ++ks){
      __builtin_amdgcn_s_setprio(1);
      #pragma unroll
      for (int nf = 0; nf < 4; ++nf){
        int rk = nf*16 + l15;
        bf16x8 ak = *(const bf16x8*)((const char*)(&Ks[buf][0]) + rk*128 + (((ks*4 + kg) ^ (rk & 7)) * 16));
        ST[nf] = __builtin_amdgcn_mfma_f32_16x16x32_bf16(ak, qf[ks], ST[nf], 0,0,0);
      }
      __builtin_amdgcn_s_setprio(0);
    }
    if (kb == qi){   // diagonal block: mask k > q
      #pragma unroll
      for (int nf = 0; nf < 4; ++nf)
        #pragma unroll
        for (int j = 0; j < 4; ++j)
          if (nf*16 + kg*4 + j > qloc) ST[nf][j] = -1e30f;
    }
    // q-local softmax: row max over 16 local + 2 shfl (lanes q,q+16,q+32,q+48)
    float mx0 = fmaxf(fmaxf(ST[0][0], ST[0][1]), fmaxf(ST[0][2], ST[0][3]));
    float mx1 = fmaxf(fmaxf(ST[1][0], ST[1][1]), fmaxf(ST[1][2], ST[1][3]));
    float mx2 = fmaxf(fmaxf(ST[2][0], ST[2][1]), fmaxf(ST[2][2], ST[2][3]));
    float mx3 = fmaxf(fmaxf(ST[3][0], ST[3][1]), fmaxf(ST[3][2], ST[3][3]));
    float pmax = fmaxf(fmaxf(mx0, mx1), fmaxf(mx2, mx3));
    pmax = fmaxf(pmax, __shfl_xor(pmax, 16, 64));
    pmax = fmaxf(pmax, __shfl_xor(pmax, 32, 64));
    // defer-max (T13): skip rescale when max growth <= 8 (P bounded by e^8, f32 accum ok)
    if (!__all(pmax <= m + 8.0f)){
      float mn = fmaxf(m, pmax);
      float fj = __expf(m - mn);
      m = mn;
      l *= fj;
      #pragma unroll
      for (int df = 0; df < 4; ++df)
        #pragma unroll
        for (int j = 0; j < 4; ++j) Ot[df][j] *= fj;
    }
    // P = exp(S - m), packed bf16 -> per-wave LDS (no barrier: wave-private)
    float rsn[4];
    unsigned int pk[4][2];
    #pragma unroll
    for (int nf = 0; nf < 4; ++nf){
      float p0 = __expf(ST[nf][0] - m), p1 = __expf(ST[nf][1] - m);
      float p2 = __expf(ST[nf][2] - m), p3 = __expf(ST[nf][3] - m);
      rsn[nf] = (p0 + p1) + (p2 + p3);
      pk[nf][0] = cvtpk(p0, p1);
      pk[nf][1] = cvtpk(p2, p3);
    }
    float rs = (rsn[0] + rsn[1]) + (rsn[2] + rsn[3]);
    rs += __shfl_xor(rs, 16, 64);
    rs += __shfl_xor(rs, 32, 64);
    l += rs;
    #pragma unroll
    for (int nf = 0; nf < 4; ++nf)
      *(uint2*)(pwb + ((nf*32 + kg*8) ^ swz)) = make_uint2(pk[nf][0], pk[nf][1]);
    // O^T += V^T · P : Ot[df] col=l15=q, row=kg*4+j=d-sub
    #pragma unroll
    for (int ks = 0; ks < 2; ++ks){
      bf16x8 pa = *(const bf16x8*)(pwb + ((ks*64 + kg*16) ^ swz));
      __builtin_amdgcn_s_setprio(1);
      #pragma unroll
      for (int df = 0; df < 4; ++df){
        int rv = df*16 + l15;
        bf16x8 vb = *(const bf16x8*)((const char*)(&Vts[buf][0]) + rv*128 + (((ks*4 + kg) ^ (rv & 7)) * 16));
        Ot[df] = __builtin_amdgcn_mfma_f32_16x16x32_bf16(vb, pa, Ot[df], 0,0,0);
      }
      __builtin_amdgcn_s_setprio(0);
    }
    __syncthreads();   // drains prefetch vmcnt + all waves' reads of buf
  }

  // epilogue: O /= l (all lane-local), hi/lo split, 8B vector stores
  const int bi = bh >> 4, h = bh & 15;
  const float rinv = 1.0f / l;
  const size_t row = (size_t)(bi*2048 + qi*64 + qloc);
  #pragma unroll
  for (int df = 0; df < 4; ++df){
    int colb = h*64 + df*16 + kg*4;
    u16x4 hv, lv;
    #pragma unroll
    for (int j = 0; j < 4; ++j){
      float v = Ot[df][j] * rinv;
      unsigned short hvv = f2bf(v);
      hv[j] = hvv;
      lv[j] = f2bf(v - bf2f(hvv));
    }
    *(u16x4*)(Ohi + row*1024 + colb) = hv;
    *(u16x4*)(Olo + row*1024 + colb) = lv;
  }
}

extern "C" void kernel_launch(void* const* d_in, const int* in_sizes, int n_in,
                              void* d_out, int out_size, void* d_ws, size_t ws_size,
                              hipStream_t stream){
  const float* x  = (const float*)d_in[0];
  const float* Wq = (const float*)d_in[1];
  const float* bq = (const float*)d_in[2];
  const float* Wk = (const float*)d_in[3];
  const float* bk = (const float*)d_in[4];
  const float* Wv = (const float*)d_in[5];
  const float* bv = (const float*)d_in[6];
  const float* Wo = (const float*)d_in[7];
  const float* bo = (const float*)d_in[8];
  const float* scale = (const float*)d_in[9];
  float* out = (float*)d_out;

  char* ws = (char*)d_ws;
  const size_t MB = 1024*1024;
  unsigned short* xh  = (unsigned short*)(ws + 0*MB);    // 8 MB
  unsigned short* wh  = (unsigned short*)(ws + 16*MB);   // 8 MB (Wq,Wk,Wv,Wo bf16)
  unsigned short* Qb  = (unsigned short*)(ws + 32*MB);
  unsigned short* Kb  = (unsigned short*)(ws + 40*MB);
  unsigned short* Vtb = (unsigned short*)(ws + 48*MB);
  unsigned short* Ohi = (unsigned short*)(ws + 56*MB);
  unsigned short* Olo = (unsigned short*)(ws + 64*MB);
  float* bias_cat     = (float*)(ws + 72*MB);

  hipLaunchKernelGGL(k_prep, dim3(2048), dim3(256), 0, stream,
                     x, Wq, Wk, Wv, Wo, bq, bk, bv, xh, wh, bias_cat);
  hipLaunchKernelGGL((k_gemm<128,0,0>), dim3(24,32), dim3(256), 0, stream,
                     xh, (const unsigned short*)nullptr, wh, bias_cat, scale,
                     Qb, Kb, Vtb, (float*)nullptr);
  hipLaunchKernelGGL(k_attn, dim3(1024), dim3(256), 0, stream, Qb, Kb, Vtb, Ohi, Olo);
  hipLaunchKernelGGL((k_gemm<128,1,1>), dim3(8,32), dim3(256), 0, stream,
                     Ohi, Olo, wh + 3u*1048576u, bo, (const float*)nullptr,
                     (unsigned short*)nullptr, (unsigned short*)nullptr,
                     (unsigned short*)nullptr, out);
}

// Round 5
// 205.937 us; speedup vs baseline: 1.4266x; 1.0436x over previous
//
#include <hip/hip_runtime.h>

// MemoryEfficientAttention: x->(Q,K,V) proj (bf16 MFMA, scale*log2e folded into Q),
// chunked-mask flash attention (double-swapped MFMA, exp2-domain q-lane-local softmax),
// O-proj (split-A bf16x2 MFMA, 64x64 tile for occupancy). fp32 in/out.
// Mask: past blocks masked, diagonal block causal, future blocks visible.

typedef __attribute__((ext_vector_type(8))) short bf16x8;
typedef __attribute__((ext_vector_type(4))) float f32x4;
typedef __attribute__((ext_vector_type(4))) float float4v;
typedef __attribute__((ext_vector_type(4))) unsigned short u16x4;

__device__ __forceinline__ unsigned short f2bf(float x){
  union { float f; unsigned int u; } c; c.f = x;
  unsigned int r = c.u + 0x7FFFu + ((c.u >> 16) & 1u);
  return (unsigned short)(r >> 16);
}
__device__ __forceinline__ float bf2f(unsigned short h){
  union { unsigned int u; float f; } c; c.u = ((unsigned int)h) << 16;
  return c.f;
}
__device__ __forceinline__ f32x4 zero4(){ f32x4 v; v[0]=0.f; v[1]=0.f; v[2]=0.f; v[3]=0.f; return v; }
__device__ __forceinline__ unsigned int cvtpk(float a, float b){
  unsigned int r;
  asm("v_cvt_pk_bf16_f32 %0, %1, %2" : "=v"(r) : "v"(a), "v"(b));
  return r;
}
__device__ __forceinline__ float exp2x(float x){   // raw v_exp_f32 = 2^x
  float r;
  asm("v_exp_f32 %0, %1" : "=v"(r) : "v"(x));
  return r;
}

// async global->LDS, 16B per lane; LDS dest wave-uniform, global src per-lane
#define GLDS16(g, l) __builtin_amdgcn_global_load_lds( \
  (const __attribute__((address_space(1))) void*)(g), \
  (__attribute__((address_space(3))) void*)(l), 16, 0, 0)

// ---------------- prep: cast x and all weights to bf16, gather biases ----------------
__global__ __launch_bounds__(256) void k_prep(
    const float* __restrict__ x,
    const float* __restrict__ Wq, const float* __restrict__ Wk,
    const float* __restrict__ Wv, const float* __restrict__ Wo,
    const float* __restrict__ bq, const float* __restrict__ bk, const float* __restrict__ bv,
    unsigned short* __restrict__ xh, unsigned short* __restrict__ wh,
    float* __restrict__ bias_cat){
  const int NX = 1048576;                     // x float4 count (4096*1024/4)
  const int NTOT = 2097152;                   // + 4 weight matrices
  int i = blockIdx.x * 256 + threadIdx.x;
  if (i < 3072){
    const float* bs[3] = {bq, bk, bv};
    bias_cat[i] = bs[i >> 10][i & 1023];
  }
  int stride = gridDim.x * 256;
  for (; i < NTOT; i += stride){
    float4v v;
    u16x4 h;
    if (i < NX){
      v = ((const float4v*)x)[i];
      #pragma unroll
      for (int j = 0; j < 4; ++j) h[j] = f2bf(v[j]);
      ((u16x4*)xh)[i] = h;
    } else {
      int jj = i - NX;
      const float* srcs[4] = {Wq, Wk, Wv, Wo};
      v = ((const float4v*)srcs[jj >> 18])[jj & 0x3FFFF];
      #pragma unroll
      for (int j = 0; j < 4; ++j) h[j] = f2bf(v[j]);
      ((u16x4*)wh)[jj] = h;
    }
  }
}

// ---------------- GEMM: out = A @ W^T + bias ----------------
// MODE 0: N=3072 fused QKV -> scatter Q[b,h,t,d]*scale*log2e, K[b,h,t,d], Vt[b,h,d,t]
// MODE 1: N=1024 -> fp32 out + bias
template<int BM, int BN, int MODE, int SPLITA>
__global__ __launch_bounds__(256) void k_gemm(
    const unsigned short* __restrict__ Ah, const unsigned short* __restrict__ Al,
    const unsigned short* __restrict__ Bh,
    const float* __restrict__ bias, const float* __restrict__ scale_p,
    unsigned short* __restrict__ oq, unsigned short* __restrict__ okk,
    unsigned short* __restrict__ ov, float* __restrict__ fo)
{
  constexpr int MF = (BN == 128) ? (BM/32) : (BM/64);  // 128x128: 4 (2x2 waves); 64x64: 1 (4x1)
  constexpr int NF = 4;
  constexpr int AISS = BM/64;
  constexpr int BISS = BN/64;
  constexpr int NA = SPLITA ? 2 : 1;
  __shared__ unsigned short As[NA][BM*32];
  __shared__ unsigned short Bs[BN*32];

  const int tid  = threadIdx.x;
  const int wid  = tid >> 6;
  const int lane = tid & 63;
  const int l15  = lane & 15;
  const int kg   = lane >> 4;
  const int m0 = blockIdx.y * BM;
  const int n0 = blockIdx.x * BN;
  const int wrb = (BN == 128) ? (wid >> 1) * (BM/2) : wid * (BM/4);
  const int wcb = (BN == 128) ? (wid & 1) * 64 : 0;
  const float qs = (MODE == 0) ? scale_p[0] * 1.4426950408889634f : 0.f;  // fold log2e

  f32x4 acc[MF][NF];
  #pragma unroll
  for (int a = 0; a < MF; ++a)
    #pragma unroll
    for (int b = 0; b < NF; ++b) acc[a][b] = zero4();

  for (int k0 = 0; k0 < 1024; k0 += 32){
    #pragma unroll
    for (int p = 0; p < NA; ++p){
      const unsigned short* Asrc = p ? Al : Ah;
      #pragma unroll
      for (int iss = 0; iss < AISS; ++iss){
        int L = iss*2048 + tid*8;
        int row = L >> 5;
        int ck = ((L >> 3) & 3) ^ ((row >> 1) & 3);
        GLDS16(Asrc + (size_t)(m0 + row)*1024 + k0 + ck*8,
               (char*)(&As[p][0]) + iss*4096 + wid*1024);
      }
    }
    #pragma unroll
    for (int iss = 0; iss < BISS; ++iss){
      int L = iss*2048 + tid*8;
      int row = L >> 5;
      int ck = ((L >> 3) & 3) ^ ((row >> 1) & 3);
      GLDS16(Bh + (size_t)(n0 + row)*1024 + k0 + ck*8,
             (char*)(&Bs[0]) + iss*4096 + wid*1024);
    }
    __syncthreads();

    bf16x8 af[MF][NA];
    #pragma unroll
    for (int mf = 0; mf < MF; ++mf){
      int r = wrb + mf*16 + l15;
      int ckpos = kg ^ ((r >> 1) & 3);
      #pragma unroll
      for (int p = 0; p < NA; ++p)
        af[mf][p] = *(const bf16x8*)((const char*)(&As[p][0]) + r*64 + ckpos*16);
    }
    #pragma unroll
    for (int nf = 0; nf < NF; ++nf){
      int r = wcb + nf*16 + l15;
      int ckpos = kg ^ ((r >> 1) & 3);
      bf16x8 bhv = *(const bf16x8*)((const char*)(&Bs[0]) + r*64 + ckpos*16);
      #pragma unroll
      for (int mf = 0; mf < MF; ++mf){
        acc[mf][nf] = __builtin_amdgcn_mfma_f32_16x16x32_bf16(af[mf][0], bhv, acc[mf][nf], 0,0,0);
        if (SPLITA)
          acc[mf][nf] = __builtin_amdgcn_mfma_f32_16x16x32_bf16(af[mf][1], bhv, acc[mf][nf], 0,0,0);
      }
    }
    __syncthreads();
  }

  #pragma unroll
  for (int mf = 0; mf < MF; ++mf){
    #pragma unroll
    for (int nf = 0; nf < NF; ++nf){
      int colg = n0 + wcb + nf*16 + l15;
      float bb = bias[colg];
      #pragma unroll
      for (int j = 0; j < 4; ++j){
        int r = m0 + wrb + mf*16 + kg*4 + j;
        float val = acc[mf][nf][j] + bb;
        if (MODE == 1){
          fo[(size_t)r*1024 + colg] = val;
        } else {
          int bi = r >> 11, tt = r & 2047;
          int mat = colg >> 10, jj = colg & 1023;
          int h = jj >> 6, d = jj & 63;
          size_t bh_ = (size_t)(bi*16 + h);
          if (mat == 0)      oq [(bh_*2048 + tt)*64 + d] = f2bf(val * qs);
          else if (mat == 1) okk[(bh_*2048 + tt)*64 + d] = f2bf(val);
          else               ov [(bh_*64 + d)*2048 + tt] = f2bf(val);  // V^T
        }
      }
    }
  }
}

// ---------------- flash attention, double-swapped MFMA, exp2 domain ----------------
// grid: 1024 = qi*32 + bh (heavy qi first). 4 waves x 16 q; q lane-local (l15).
// ST = mfma(K,Q): col=l15=q, row=kg*4+j=k.  Ot = mfma(V^T,P^T): col=l15=q, row=d.
// Qs LDS is reused as the per-wave P tile after the (one-time) Q-fragment load:
// wave w's qf slice == wave w's P slice == bytes [w*2048, w*2048+2048).
__global__ __launch_bounds__(256) void k_attn(
    const unsigned short* __restrict__ Qg, const unsigned short* __restrict__ Kg,
    const unsigned short* __restrict__ Vtg,
    unsigned short* __restrict__ Ohi, unsigned short* __restrict__ Olo)
{
  __shared__ unsigned short Qs[64*64];       // Q tile -> P tiles (40KB total LDS)
  __shared__ unsigned short Ks[2][64*64];
  __shared__ unsigned short Vts[2][64*64];   // rows = d, cols = kv

  const int tid  = threadIdx.x;
  const int wid  = tid >> 6;
  const int lane = tid & 63;
  const int l15  = lane & 15;
  const int kg   = lane >> 4;
  const int qi = blockIdx.x >> 5;
  const int bh = blockIdx.x & 31;
  const size_t base = (size_t)bh * (2048*64);

  // hoisted staging pointers: per-lane global src, advanced by constants per tile
  const int r0 = tid >> 3;                       // staging row for iss0 (iss1 = r0+32)
  const int ck = ((tid & 7) ^ (r0 & 7)) * 8;     // swizzled chunk (same for both iss)
  const unsigned short* qp = Qg  + base + (size_t)(qi*64 + r0)*64 + ck;
  const unsigned short* kp = Kg  + base + (size_t)(qi*64 + r0)*64 + ck;
  const unsigned short* vp = Vtg + base + (size_t)r0*2048 + qi*64 + ck;

  GLDS16(qp,         (char*)Qs  + wid*1024);
  GLDS16(qp + 2048,  (char*)Qs  + wid*1024 + 4096);
  GLDS16(kp,         (char*)Ks  + wid*1024);
  GLDS16(kp + 2048,  (char*)Ks  + wid*1024 + 4096);
  GLDS16(vp,         (char*)Vts + wid*1024);
  GLDS16(vp + 65536, (char*)Vts + wid*1024 + 4096);
  kp += 4096;  vp += 64;                         // -> tile qi+1
  __syncthreads();

  // hoisted LDS read offsets: all reads are base + {c0,c1} + imm
  const int c0 = (kg ^ (l15 & 7)) << 4;
  const int c1 = c0 ^ 64;
  const char* qbase = (const char*)Qs + wid*2048 + l15*128;  // qf slice == P slice
  char* pwb = (char*)Qs + wid*2048 + l15*128;
  const int pws = (kg*8) ^ ((l15 & 7) << 4);

  const bf16x8 qf0 = *(const bf16x8*)(qbase + c0);
  const bf16x8 qf1 = *(const bf16x8*)(qbase + c1);

  f32x4 Ot[4];
  #pragma unroll
  for (int d = 0; d < 4; ++d) Ot[d] = zero4();
  float m = -1e30f, l = 0.f;
  const int qloc = wid*16 + l15;

  for (int kb = qi; kb < 32; ++kb){
    const int buf = (kb - qi) & 1;
    const char* ksb = (const char*)Ks  + buf*8192 + l15*128;
    const char* vsb = (const char*)Vts + buf*8192 + l15*128;
    // prefetch next K/V into other buffer (drained by closing barrier)
    if (kb + 1 < 32){
      char* dK = (char*)Ks  + (buf^1)*8192 + wid*1024;
      char* dV = (char*)Vts + (buf^1)*8192 + wid*1024;
      GLDS16(kp,         dK);
      GLDS16(kp + 2048,  dK + 4096);
      GLDS16(vp,         dV);
      GLDS16(vp + 65536, dV + 4096);
      kp += 4096;  vp += 64;
    }
    // S^T = K·Q^T (log2-domain: scale*log2e folded into Q)
    f32x4 ST[4];
    #pragma unroll
    for (int nf = 0; nf < 4; ++nf) ST[nf] = zero4();
    __builtin_amdgcn_s_setprio(1);
    #pragma unroll
    for (int nf = 0; nf < 4; ++nf){
      bf16x8 ak = *(const bf16x8*)(ksb + nf*2048 + c0);
      ST[nf] = __builtin_amdgcn_mfma_f32_16x16x32_bf16(ak, qf0, ST[nf], 0,0,0);
    }
    #pragma unroll
    for (int nf = 0; nf < 4; ++nf){
      bf16x8 ak = *(const bf16x8*)(ksb + nf*2048 + c1);
      ST[nf] = __builtin_amdgcn_mfma_f32_16x16x32_bf16(ak, qf1, ST[nf], 0,0,0);
    }
    __builtin_amdgcn_s_setprio(0);
    if (kb == qi){   // diagonal block: mask k > q
      #pragma unroll
      for (int nf = 0; nf < 4; ++nf)
        #pragma unroll
        for (int j = 0; j < 4; ++j)
          if (nf*16 + kg*4 + j > qloc) ST[nf][j] = -1e30f;
    }
    // q-local softmax (exp2 domain): 15 local fmax + 2 shfl
    float mx0 = fmaxf(fmaxf(ST[0][0], ST[0][1]), fmaxf(ST[0][2], ST[0][3]));
    float mx1 = fmaxf(fmaxf(ST[1][0], ST[1][1]), fmaxf(ST[1][2], ST[1][3]));
    float mx2 = fmaxf(fmaxf(ST[2][0], ST[2][1]), fmaxf(ST[2][2], ST[2][3]));
    float mx3 = fmaxf(fmaxf(ST[3][0], ST[3][1]), fmaxf(ST[3][2], ST[3][3]));
    float pmax = fmaxf(fmaxf(mx0, mx1), fmaxf(mx2, mx3));
    pmax = fmaxf(pmax, __shfl_xor(pmax, 16, 64));
    pmax = fmaxf(pmax, __shfl_xor(pmax, 32, 64));
    // defer-max (T13): skip rescale while growth <= 8 (P bounded by 2^8, f32 accum ok)
    if (!__all(pmax <= m + 8.0f)){
      float mn = fmaxf(m, pmax);
      float fj = exp2x(m - mn);
      m = mn;
      l *= fj;
      #pragma unroll
      for (int df = 0; df < 4; ++df)
        #pragma unroll
        for (int j = 0; j < 4; ++j) Ot[df][j] *= fj;
    }
    // P = 2^(S-m), packed bf16 -> per-wave P slice (wave-private, no barrier)
    float rsn[4];
    unsigned int pk[4][2];
    #pragma unroll
    for (int nf = 0; nf < 4; ++nf){
      float p0 = exp2x(ST[nf][0] - m), p1 = exp2x(ST[nf][1] - m);
      float p2 = exp2x(ST[nf][2] - m), p3 = exp2x(ST[nf][3] - m);
      rsn[nf] = (p0 + p1) + (p2 + p3);
      pk[nf][0] = cvtpk(p0, p1);
      pk[nf][1] = cvtpk(p2, p3);
    }
    float rs = (rsn[0] + rsn[1]) + (rsn[2] + rsn[3]);
    rs += __shfl_xor(rs, 16, 64);
    rs += __shfl_xor(rs, 32, 64);
    l += rs;
    #pragma unroll
    for (int nf = 0; nf < 4; ++nf)
      *(uint2*)(pwb + (pws ^ (nf*32))) = make_uint2(pk[nf][0], pk[nf][1]);
    // O^T += V^T · P
    {
      bf16x8 pa0 = *(const bf16x8*)(qbase + c0);
      bf16x8 pa1 = *(const bf16x8*)(qbase + c1);
      __builtin_amdgcn_s_setprio(1);
      #pragma unroll
      for (int df = 0; df < 4; ++df){
        bf16x8 vb = *(const bf16x8*)(vsb + df*2048 + c0);
        Ot[df] = __builtin_amdgcn_mfma_f32_16x16x32_bf16(vb, pa0, Ot[df], 0,0,0);
      }
      #pragma unroll
      for (int df = 0; df < 4; ++df){
        bf16x8 vb = *(const bf16x8*)(vsb + df*2048 + c1);
        Ot[df] = __builtin_amdgcn_mfma_f32_16x16x32_bf16(vb, pa1, Ot[df], 0,0,0);
      }
      __builtin_amdgcn_s_setprio(0);
    }
    __syncthreads();   // drains prefetch vmcnt + all waves' reads of buf
  }

  // epilogue: O /= l (lane-local), hi/lo split, 8B vector stores
  const int bi = bh >> 4, h = bh & 15;
  const float rinv = 1.0f / l;
  const size_t row = (size_t)(bi*2048 + qi*64 + qloc);
  #pragma unroll
  for (int df = 0; df < 4; ++df){
    int colb = h*64 + df*16 + kg*4;
    u16x4 hv, lv;
    #pragma unroll
    for (int j = 0; j < 4; ++j){
      float v = Ot[df][j] * rinv;
      unsigned short hvv = f2bf(v);
      hv[j] = hvv;
      lv[j] = f2bf(v - bf2f(hvv));
    }
    *(u16x4*)(Ohi + row*1024 + colb) = hv;
    *(u16x4*)(Olo + row*1024 + colb) = lv;
  }
}

extern "C" void kernel_launch(void* const* d_in, const int* in_sizes, int n_in,
                              void* d_out, int out_size, void* d_ws, size_t ws_size,
                              hipStream_t stream){
  const float* x  = (const float*)d_in[0];
  const float* Wq = (const float*)d_in[1];
  const float* bq = (const float*)d_in[2];
  const float* Wk = (const float*)d_in[3];
  const float* bk = (const float*)d_in[4];
  const float* Wv = (const float*)d_in[5];
  const float* bv = (const float*)d_in[6];
  const float* Wo = (const float*)d_in[7];
  const float* bo = (const float*)d_in[8];
  const float* scale = (const float*)d_in[9];
  float* out = (float*)d_out;

  char* ws = (char*)d_ws;
  const size_t MB = 1024*1024;
  unsigned short* xh  = (unsigned short*)(ws + 0*MB);    // 8 MB
  unsigned short* wh  = (unsigned short*)(ws + 16*MB);   // 8 MB (Wq,Wk,Wv,Wo bf16)
  unsigned short* Qb  = (unsigned short*)(ws + 32*MB);
  unsigned short* Kb  = (unsigned short*)(ws + 40*MB);
  unsigned short* Vtb = (unsigned short*)(ws + 48*MB);
  unsigned short* Ohi = (unsigned short*)(ws + 56*MB);
  unsigned short* Olo = (unsigned short*)(ws + 64*MB);
  float* bias_cat     = (float*)(ws + 72*MB);

  hipLaunchKernelGGL(k_prep, dim3(2048), dim3(256), 0, stream,
                     x, Wq, Wk, Wv, Wo, bq, bk, bv, xh, wh, bias_cat);
  hipLaunchKernelGGL((k_gemm<128,128,0,0>), dim3(24,32), dim3(256), 0, stream,
                     xh, (const unsigned short*)nullptr, wh, bias_cat, scale,
                     Qb, Kb, Vtb, (float*)nullptr);
  hipLaunchKernelGGL(k_attn, dim3(1024), dim3(256), 0, stream, Qb, Kb, Vtb, Ohi, Olo);
  hipLaunchKernelGGL((k_gemm<64,64,1,1>), dim3(16,64), dim3(256), 0, stream,
                     Ohi, Olo, wh + 3u*1048576u, bo, (const float*)nullptr,
                     (unsigned short*)nullptr, (unsigned short*)nullptr,
                     (unsigned short*)nullptr, out);
}